// Round 1
// baseline (264.842 us; speedup 1.0000x reference)
//
#include <hip/hip_runtime.h>
#include <hip/hip_bf16.h>
#include <cstdint>
#include <cstddef>

// Problem constants: B=4, S=2048, D_IN=D_OUT=768
// Decomposition: QKV-proj GEMM (f16 MFMA) -> QK^T GEMM (causal-skipped) ->
// row softmax -> PV GEMM (causal K-truncated). Scores fp32 in ws.

typedef _Float16 f16x8 __attribute__((ext_vector_type(8)));
typedef _Float16 f16x4 __attribute__((ext_vector_type(4)));
typedef float    f32x4 __attribute__((ext_vector_type(4)));

__device__ __forceinline__ void gload_lds16(const void* g, void* l) {
    __builtin_amdgcn_global_load_lds(
        (const __attribute__((address_space(1))) void*)g,
        (__attribute__((address_space(3))) void*)l, 16, 0, 0);
}

// C = A[M,K] * B[N,K]^T, f16 inputs, fp32 accum.
// 128x128 tile, 256 threads = 4 waves (2x2), each wave 64x64 = 4x4 MFMA frags.
// EPI 0: QKV projection epilogue (split Q/K flat f16, V transposed per batch)
// EPI 1: scores fp32, skip tiles above diagonal
// EPI 2: output fp32, K-loop truncated causally
template <int EPI>
__global__ __launch_bounds__(256) void gemm_bt(
    const _Float16* __restrict__ A, const _Float16* __restrict__ B,
    float* __restrict__ CF,
    _Float16* __restrict__ OQ, _Float16* __restrict__ OKk, _Float16* __restrict__ OV,
    int K, int lda, int ldb, int ldc,
    long long batchA, long long batchB, long long batchC)
{
    const int tm = blockIdx.y, tn = blockIdx.x, bz = blockIdx.z;
    if (EPI == 1 && tn > tm) return;   // fully-masked score tile

    const int m0 = tm * 128, n0 = tn * 128;
    const int tid  = threadIdx.x;
    const int lane = tid & 63, wave = tid >> 6;
    const int wm = (wave >> 1) * 64, wn = (wave & 1) * 64;
    const int qr = lane >> 4, ql = lane & 15;

    __shared__ _Float16 sA[128 * 32];
    __shared__ _Float16 sB[128 * 32];

    const _Float16* Ab = A + (long long)bz * batchA + (long long)m0 * lda;
    const _Float16* Bb = B + (long long)bz * batchB + (long long)n0 * ldb;

    int kIters = K / 32;
    if (EPI == 2) kIters = (tm + 1) * 4;   // P is zero beyond (tm+1)*128

    f32x4 acc[4][4];
#pragma unroll
    for (int i = 0; i < 4; ++i)
#pragma unroll
        for (int j = 0; j < 4; ++j) acc[i][j] = (f32x4){0.f, 0.f, 0.f, 0.f};

    // staging: chunk c = j*256 + tid covers LDS bytes [c*16, c*16+16)
    const int c0 = tid,       r0 = c0 >> 2, col0 = (c0 & 3) << 3;
    const int c1 = tid + 256, r1 = c1 >> 2, col1 = (c1 & 3) << 3;
    _Float16* ldsA0 = sA + (wave * 64) * 8;
    _Float16* ldsA1 = sA + (256 + wave * 64) * 8;
    _Float16* ldsB0 = sB + (wave * 64) * 8;
    _Float16* ldsB1 = sB + (256 + wave * 64) * 8;

    for (int kt = 0; kt < kIters; ++kt) {
        const int kk = kt * 32;
        gload_lds16(Ab + (long long)r0 * lda + kk + col0, ldsA0);
        gload_lds16(Ab + (long long)r1 * lda + kk + col1, ldsA1);
        gload_lds16(Bb + (long long)r0 * ldb + kk + col0, ldsB0);
        gload_lds16(Bb + (long long)r1 * ldb + kk + col1, ldsB1);
        __syncthreads();   // drains vmcnt (global_load_lds) before reads

        f16x8 aF[4], bF[4];
#pragma unroll
        for (int mi = 0; mi < 4; ++mi)
            aF[mi] = *(const f16x8*)&sA[(wm + mi * 16 + ql) * 32 + qr * 8];
#pragma unroll
        for (int ni = 0; ni < 4; ++ni)
            bF[ni] = *(const f16x8*)&sB[(wn + ni * 16 + ql) * 32 + qr * 8];

#pragma unroll
        for (int mi = 0; mi < 4; ++mi)
#pragma unroll
            for (int ni = 0; ni < 4; ++ni)
                acc[mi][ni] = __builtin_amdgcn_mfma_f32_16x16x32_f16(
                    aF[mi], bF[ni], acc[mi][ni], 0, 0, 0);

        __syncthreads();   // protect LDS before next stage
    }

    // Epilogue. C/D frag: col = lane&15, row = (lane>>4)*4 + r  [m89/m91-verified]
    const long long zC = (long long)bz * batchC;
#pragma unroll
    for (int mi = 0; mi < 4; ++mi) {
#pragma unroll
        for (int ni = 0; ni < 4; ++ni) {
            const f32x4 v = acc[mi][ni];
            const int mbase = m0 + wm + mi * 16 + qr * 4;
            const int n     = n0 + wn + ni * 16 + ql;
#pragma unroll
            for (int r = 0; r < 4; ++r) {
                const int m = mbase + r;
                const float val = v[r];
                if (EPI == 0) {
                    const int b = m >> 11, s = m & 2047;
                    if (n < 768)
                        OQ[(long long)m * 768 + n] = (_Float16)val;
                    else if (n < 1536)
                        OKk[(long long)m * 768 + (n - 768)] = (_Float16)val;
                    else
                        OV[((long long)b * 768 + (n - 1536)) * 2048 + s] = (_Float16)val;
                } else {
                    CF[zC + (long long)m * ldc + n] = val;
                }
            }
        }
    }
}

// One block (256 threads) per row. Causal softmax over j<=i, writes f16 P
// (zeros above diagonal).
__global__ __launch_bounds__(256) void softmax_causal(
    const float* __restrict__ Sc, _Float16* __restrict__ P)
{
    const int row = blockIdx.x;          // b*2048 + i
    const int i   = row & 2047;
    const float* srow = Sc + (long long)row * 2048;
    _Float16*    prow = P  + (long long)row * 2048;
    const int L = i + 1;
    const float scale = 0.03608439182435161f;   // 1/sqrt(768)
    const int tid = threadIdx.x, lane = tid & 63, wave = tid >> 6;

    float vals[8];
    float lmax = -1e30f;
#pragma unroll
    for (int t = 0; t < 8; ++t) {
        const int j = tid + t * 256;
        const float v = (j < L) ? srow[j] * scale : -1e30f;
        vals[t] = v;
        lmax = fmaxf(lmax, v);
    }
#pragma unroll
    for (int off = 32; off > 0; off >>= 1)
        lmax = fmaxf(lmax, __shfl_xor(lmax, off));

    __shared__ float red[4];
    if (lane == 0) red[wave] = lmax;
    __syncthreads();
    const float gmax = fmaxf(fmaxf(red[0], red[1]), fmaxf(red[2], red[3]));
    __syncthreads();

    float lsum = 0.f;
#pragma unroll
    for (int t = 0; t < 8; ++t) {
        const float e = __expf(vals[t] - gmax);   // masked -> exp(-huge)=0
        vals[t] = e;
        lsum += e;
    }
#pragma unroll
    for (int off = 32; off > 0; off >>= 1)
        lsum += __shfl_xor(lsum, off);
    if (lane == 0) red[wave] = lsum;
    __syncthreads();
    const float inv = 1.f / (red[0] + red[1] + red[2] + red[3]);

#pragma unroll
    for (int t = 0; t < 8; ++t) {
        const int j = tid + t * 256;
        prow[j] = (_Float16)(vals[t] * inv);
    }
}

__global__ __launch_bounds__(256) void cvt_f32_f16_v4(
    const float* __restrict__ in, _Float16* __restrict__ out, int n4)
{
    const int i = blockIdx.x * 256 + threadIdx.x;
    if (i < n4) {
        const float4 v = ((const float4*)in)[i];
        f16x4 o = { (_Float16)v.x, (_Float16)v.y, (_Float16)v.z, (_Float16)v.w };
        *(f16x4*)(out + (long long)i * 4) = o;
    }
}

extern "C" void kernel_launch(void* const* d_in, const int* in_sizes, int n_in,
                              void* d_out, int out_size, void* d_ws, size_t ws_size,
                              hipStream_t stream) {
    const float* x  = (const float*)d_in[0];
    const float* wq = (const float*)d_in[1];
    const float* wk = (const float*)d_in[2];
    const float* wv = (const float*)d_in[3];
    float* out = (float*)d_out;
    char* ws = (char*)d_ws;

    size_t off = 0;
    auto alloc = [&](size_t bytes) {
        void* p = ws + off;
        off = (off + bytes + 255) & ~(size_t)255;
        return p;
    };
    _Float16* xh = (_Float16*)alloc(8192ll * 768 * 2);
    _Float16* Wh = (_Float16*)alloc(2304ll * 768 * 2);
    _Float16* Qh = (_Float16*)alloc(8192ll * 768 * 2);
    _Float16* Kh = (_Float16*)alloc(8192ll * 768 * 2);
    _Float16* Vt = (_Float16*)alloc(4ll * 768 * 2048 * 2);     // V^T per batch
    float*    Sc = (float*)   alloc(4ll * 2048 * 2048 * 4);    // scores fp32
    _Float16* P  = (_Float16*)alloc(4ll * 2048 * 2048 * 2);    // softmax f16

    cvt_f32_f16_v4<<<8192 * 768 / 4 / 256, 256, 0, stream>>>(x, xh, 8192 * 768 / 4);
    cvt_f32_f16_v4<<<768 * 768 / 4 / 256, 256, 0, stream>>>(wq, Wh, 768 * 768 / 4);
    cvt_f32_f16_v4<<<768 * 768 / 4 / 256, 256, 0, stream>>>(wk, Wh + 768 * 768, 768 * 768 / 4);
    cvt_f32_f16_v4<<<768 * 768 / 4 / 256, 256, 0, stream>>>(wv, Wh + 2 * 768 * 768, 768 * 768 / 4);

    // Y = x * W^T : M=8192, N=2304, K=768
    gemm_bt<0><<<dim3(18, 64, 1), 256, 0, stream>>>(
        xh, Wh, nullptr, Qh, Kh, Vt,
        768, 768, 768, 0, 0, 0, 0);

    // S = Q * K^T per batch : M=N=2048, K=768 (lower-triangle tiles only)
    gemm_bt<1><<<dim3(16, 16, 4), 256, 0, stream>>>(
        Qh, Kh, Sc, nullptr, nullptr, nullptr,
        768, 768, 768, 2048, 2048ll * 768, 2048ll * 768, 2048ll * 2048);

    softmax_causal<<<8192, 256, 0, stream>>>(Sc, P);

    // O = P * (V^T)^T per batch : M=2048, N=768, K=2048 (K truncated causally)
    gemm_bt<2><<<dim3(6, 16, 4), 256, 0, stream>>>(
        P, Vt, out, nullptr, nullptr, nullptr,
        2048, 2048, 2048, 768, 2048ll * 2048, 768ll * 2048, 2048ll * 768);
}

// Round 2
// 231.749 us; speedup vs baseline: 1.1428x; 1.1428x over previous
//
#include <hip/hip_runtime.h>
#include <hip/hip_bf16.h>
#include <cstdint>
#include <cstddef>

// B=4, S=2048, D=768 causal attention, fp32 in/out, f16 MFMA compute.
// QKV GEMM -> QK^T (causal-skipped, f16 scores, scale fused) -> softmax ->
// PV GEMM (causal K-truncated).
// GEMM: 128x128 tile, BK=64, XOR-swizzled LDS (conflict-free ds_read_b128),
// global_load_lds width-16 staging.

typedef _Float16 f16x8 __attribute__((ext_vector_type(8)));
typedef _Float16 f16x4 __attribute__((ext_vector_type(4)));
typedef float    f32x4 __attribute__((ext_vector_type(4)));

#define SOFTMAX_SCALE 0.036084391824351615f  // 1/sqrt(768)

__device__ __forceinline__ void gload_lds16(const void* g, void* l) {
    __builtin_amdgcn_global_load_lds(
        (const __attribute__((address_space(1))) void*)g,
        (__attribute__((address_space(3))) void*)l, 16, 0, 0);
}

// C = A[M,K] * B[N,K]^T, f16 in, fp32 accum. 128x128 tile, BK=64.
// EPI 0: QKV projection epilogue (Q/K flat f16, V transposed per batch)
// EPI 1: scores f16 * SOFTMAX_SCALE, skip tiles above diagonal
// EPI 2: output fp32, K-loop truncated causally
template <int EPI>
__global__ __launch_bounds__(256) void gemm_bt(
    const _Float16* __restrict__ A, const _Float16* __restrict__ B,
    float* __restrict__ CF, _Float16* __restrict__ CH,
    _Float16* __restrict__ OQ, _Float16* __restrict__ OKk, _Float16* __restrict__ OV,
    int K, int lda, int ldb, int ldc,
    long long batchA, long long batchB, long long batchC)
{
    const int tm = blockIdx.y, tn = blockIdx.x, bz = blockIdx.z;
    if (EPI == 1 && tn > tm) return;   // fully-masked score tile

    const int m0 = tm * 128, n0 = tn * 128;
    const int tid  = threadIdx.x;
    const int lane = tid & 63, wave = tid >> 6;
    const int wm = (wave >> 1) * 64, wn = (wave & 1) * 64;
    const int qr = lane >> 4, ql = lane & 15;

    __shared__ _Float16 sA[128 * 64];
    __shared__ _Float16 sB[128 * 64];

    const _Float16* Ab = A + (long long)bz * batchA + (long long)m0 * lda;
    const _Float16* Bb = B + (long long)bz * batchB + (long long)n0 * ldb;

    int kIters = K / 64;
    if (EPI == 2) kIters = (tm + 1) * 2;   // P is zero beyond (tm+1)*128

    f32x4 acc[4][4];
#pragma unroll
    for (int i = 0; i < 4; ++i)
#pragma unroll
        for (int j = 0; j < 4; ++j) acc[i][j] = (f32x4){0.f, 0.f, 0.f, 0.f};

    // Staging: 16B chunk c = t*256 + tid; row = c>>3, stored at swizzled
    // chunk position (c&7); the data placed there is global chunk
    // (c&7)^(row&7) so that readers XOR the same way -> conflict-free.
    int srow[4], sgc[4];
#pragma unroll
    for (int t = 0; t < 4; ++t) {
        const int c = t * 256 + tid;
        const int r = c >> 3;
        srow[t] = r;
        sgc[t]  = (c & 7) ^ (r & 7);
    }

    for (int kt = 0; kt < kIters; ++kt) {
        const int kk = kt * 64;
#pragma unroll
        for (int t = 0; t < 4; ++t)
            gload_lds16(Ab + (long long)srow[t] * lda + kk + sgc[t] * 8,
                        sA + (t * 256 + wave * 64) * 8);
#pragma unroll
        for (int t = 0; t < 4; ++t)
            gload_lds16(Bb + (long long)srow[t] * ldb + kk + sgc[t] * 8,
                        sB + (t * 256 + wave * 64) * 8);
        __syncthreads();   // drains vmcnt (global_load_lds) before reads

#pragma unroll
        for (int ks = 0; ks < 2; ++ks) {
            f16x8 aF[4], bF[4];
#pragma unroll
            for (int mi = 0; mi < 4; ++mi) {
                const int r = wm + mi * 16 + ql;
                const int sc = (ks * 4 + qr) ^ (r & 7);
                aF[mi] = *(const f16x8*)&sA[r * 64 + sc * 8];
            }
#pragma unroll
            for (int ni = 0; ni < 4; ++ni) {
                const int r = wn + ni * 16 + ql;
                const int sc = (ks * 4 + qr) ^ (r & 7);
                bF[ni] = *(const f16x8*)&sB[r * 64 + sc * 8];
            }
#pragma unroll
            for (int mi = 0; mi < 4; ++mi)
#pragma unroll
                for (int ni = 0; ni < 4; ++ni)
                    acc[mi][ni] = __builtin_amdgcn_mfma_f32_16x16x32_f16(
                        aF[mi], bF[ni], acc[mi][ni], 0, 0, 0);
        }
        __syncthreads();   // protect LDS before next stage
    }

    // Epilogue. C/D frag: col = lane&15, row = (lane>>4)*4 + r
    const long long zC = (long long)bz * batchC;
#pragma unroll
    for (int mi = 0; mi < 4; ++mi) {
#pragma unroll
        for (int ni = 0; ni < 4; ++ni) {
            const f32x4 v = acc[mi][ni];
            const int mbase = m0 + wm + mi * 16 + qr * 4;
            const int n     = n0 + wn + ni * 16 + ql;
#pragma unroll
            for (int r = 0; r < 4; ++r) {
                const int m = mbase + r;
                const float val = v[r];
                if (EPI == 0) {
                    const int b = m >> 11, s = m & 2047;
                    if (n < 768)
                        OQ[(long long)m * 768 + n] = (_Float16)val;
                    else if (n < 1536)
                        OKk[(long long)m * 768 + (n - 768)] = (_Float16)val;
                    else
                        OV[((long long)b * 768 + (n - 1536)) * 2048 + s] = (_Float16)val;
                } else if (EPI == 1) {
                    CH[zC + (long long)m * ldc + n] = (_Float16)(val * SOFTMAX_SCALE);
                } else {
                    CF[zC + (long long)m * ldc + n] = val;
                }
            }
        }
    }
}

// One block (256 threads) per row; f16 scores in (pre-scaled), f16 P out.
__global__ __launch_bounds__(256) void softmax_causal(
    const _Float16* __restrict__ Sc, _Float16* __restrict__ P)
{
    const int row = blockIdx.x;          // b*2048 + i
    const int i   = row & 2047;
    const int L   = i + 1;
    const f16x8* srow = (const f16x8*)(Sc + (long long)row * 2048);
    f16x8*       prow = (f16x8*)(P + (long long)row * 2048);
    const int tid = threadIdx.x, lane = tid & 63, wave = tid >> 6;

    const f16x8 v8 = srow[tid];          // j = tid*8 + t
    float vals[8];
    float lmax = -1e30f;
#pragma unroll
    for (int t = 0; t < 8; ++t) {
        const int j = tid * 8 + t;
        const float v = (j < L) ? (float)v8[t] : -1e30f;
        vals[t] = v;
        lmax = fmaxf(lmax, v);
    }
#pragma unroll
    for (int off = 32; off > 0; off >>= 1)
        lmax = fmaxf(lmax, __shfl_xor(lmax, off));

    __shared__ float red[4];
    if (lane == 0) red[wave] = lmax;
    __syncthreads();
    const float gmax = fmaxf(fmaxf(red[0], red[1]), fmaxf(red[2], red[3]));
    __syncthreads();

    float lsum = 0.f;
#pragma unroll
    for (int t = 0; t < 8; ++t) {
        const float e = __expf(vals[t] - gmax);   // masked -> 0
        vals[t] = e;
        lsum += e;
    }
#pragma unroll
    for (int off = 32; off > 0; off >>= 1)
        lsum += __shfl_xor(lsum, off);
    if (lane == 0) red[wave] = lsum;
    __syncthreads();
    const float inv = 1.f / (red[0] + red[1] + red[2] + red[3]);

    f16x8 o;
#pragma unroll
    for (int t = 0; t < 8; ++t) o[t] = (_Float16)(vals[t] * inv);
    prow[tid] = o;
}

__global__ __launch_bounds__(256) void cvt_x(
    const float* __restrict__ in, _Float16* __restrict__ out)
{
    const int i = blockIdx.x * 256 + threadIdx.x;   // one per 8 elements
    const float4 v0 = ((const float4*)in)[i * 2];
    const float4 v1 = ((const float4*)in)[i * 2 + 1];
    f16x8 o = { (_Float16)v0.x, (_Float16)v0.y, (_Float16)v0.z, (_Float16)v0.w,
                (_Float16)v1.x, (_Float16)v1.y, (_Float16)v1.z, (_Float16)v1.w };
    ((f16x8*)out)[i] = o;
}

__global__ __launch_bounds__(256) void cvt_w3(
    const float* __restrict__ s0, const float* __restrict__ s1,
    const float* __restrict__ s2, _Float16* __restrict__ out)
{
    const int idx = blockIdx.x * 256 + threadIdx.x;  // one per 8 elements
    const int per = 768 * 768 / 8;                   // 73728 (288 blocks each)
    const int w = idx / per;                         // wave-uniform
    const float* s = (w == 0) ? s0 : (w == 1) ? s1 : s2;
    const int lo = idx - w * per;
    const float4 v0 = ((const float4*)s)[lo * 2];
    const float4 v1 = ((const float4*)s)[lo * 2 + 1];
    f16x8 o = { (_Float16)v0.x, (_Float16)v0.y, (_Float16)v0.z, (_Float16)v0.w,
                (_Float16)v1.x, (_Float16)v1.y, (_Float16)v1.z, (_Float16)v1.w };
    ((f16x8*)out)[idx] = o;
}

extern "C" void kernel_launch(void* const* d_in, const int* in_sizes, int n_in,
                              void* d_out, int out_size, void* d_ws, size_t ws_size,
                              hipStream_t stream) {
    const float* x  = (const float*)d_in[0];
    const float* wq = (const float*)d_in[1];
    const float* wk = (const float*)d_in[2];
    const float* wv = (const float*)d_in[3];
    float* out = (float*)d_out;
    char* ws = (char*)d_ws;

    size_t off = 0;
    auto alloc = [&](size_t bytes) {
        void* p = ws + off;
        off = (off + bytes + 255) & ~(size_t)255;
        return p;
    };
    _Float16* xh = (_Float16*)alloc(8192ll * 768 * 2);
    _Float16* Wh = (_Float16*)alloc(2304ll * 768 * 2);
    _Float16* Qh = (_Float16*)alloc(8192ll * 768 * 2);
    _Float16* Kh = (_Float16*)alloc(8192ll * 768 * 2);
    _Float16* Vt = (_Float16*)alloc(4ll * 768 * 2048 * 2);     // V^T per batch
    _Float16* Sc = (_Float16*)alloc(4ll * 2048 * 2048 * 2);    // scores f16 (scaled)
    _Float16* P  = (_Float16*)alloc(4ll * 2048 * 2048 * 2);    // softmax f16

    cvt_x<<<8192 * 768 / 8 / 256, 256, 0, stream>>>(x, xh);
    cvt_w3<<<3 * 288, 256, 0, stream>>>(wq, wk, wv, Wh);

    // Y = x * W^T : M=8192, N=2304, K=768
    gemm_bt<0><<<dim3(18, 64, 1), 256, 0, stream>>>(
        xh, Wh, nullptr, nullptr, Qh, Kh, Vt,
        768, 768, 768, 0, 0, 0, 0);

    // S = Q * K^T per batch : M=N=2048, K=768 (lower-triangle tiles only)
    gemm_bt<1><<<dim3(16, 16, 4), 256, 0, stream>>>(
        Qh, Kh, nullptr, Sc, nullptr, nullptr, nullptr,
        768, 768, 768, 2048, 2048ll * 768, 2048ll * 768, 2048ll * 2048);

    softmax_causal<<<8192, 256, 0, stream>>>(Sc, P);

    // O = P * (V^T)^T per batch : M=2048, N=768, K=2048 (K truncated causally)
    gemm_bt<2><<<dim3(6, 16, 4), 256, 0, stream>>>(
        P, Vt, out, nullptr, nullptr, nullptr, nullptr,
        2048, 2048, 2048, 768, 2048ll * 2048, 768ll * 2048, 2048ll * 768);
}

// Round 3
// 212.151 us; speedup vs baseline: 1.2484x; 1.0924x over previous
//
#include <hip/hip_runtime.h>
#include <hip/hip_bf16.h>
#include <cstdint>
#include <cstddef>

// B=4, S=2048, D=768 causal attention, fp32 in/out, f16 MFMA compute.
// Phases: cvt -> QKV GEMM -> QK^T GEMM (epilogue: exp+rowsum atomics, E f16)
//         -> PV GEMM (epilogue: *1/rowsum). No separate softmax pass.
// GEMM: 128x128 tile, BK=64, XOR-swizzled LDS, REGISTER-PREFETCH pipeline:
// global->VGPR loads for tile kt+1 issued before MFMA of tile kt (overlap).

typedef _Float16 f16x8 __attribute__((ext_vector_type(8)));
typedef float    f32x4 __attribute__((ext_vector_type(4)));

#define SOFTMAX_SCALE 0.036084391824351615f  // 1/sqrt(768)

// EPI 0: QKV projection epilogue (Q/K flat f16, V transposed per batch)
// EPI 1: E = exp(scale*S) f16 (causal-masked), rowsum atomics; triangular grid
// EPI 2: output fp32 * 1/rowsum[m], K-loop truncated causally
template <int EPI>
__global__ __launch_bounds__(256) void gemm_bt(
    const _Float16* __restrict__ A, const _Float16* __restrict__ B,
    float* __restrict__ CF, _Float16* __restrict__ CH,
    _Float16* __restrict__ OQ, _Float16* __restrict__ OKk, _Float16* __restrict__ OV,
    float* __restrict__ rowsum,
    int K, int lda, int ldb, int ldc,
    long long batchA, long long batchB, long long batchC)
{
    int tm, tn, bz;
    if (EPI == 1) {
        // triangular decode: 136 lower-triangle tiles per batch
        const int idx = blockIdx.x;
        bz = idx / 136;
        const int t = idx - bz * 136;
        tm = (int)((__builtin_sqrtf(8.f * t + 1.f) - 1.f) * 0.5f);
        while ((tm + 1) * (tm + 2) / 2 <= t) ++tm;
        while (tm * (tm + 1) / 2 > t) --tm;
        tn = t - tm * (tm + 1) / 2;
    } else {
        tm = blockIdx.y; tn = blockIdx.x; bz = blockIdx.z;
    }

    const int m0 = tm * 128, n0 = tn * 128;
    const int tid  = threadIdx.x;
    const int lane = tid & 63, wave = tid >> 6;
    const int wm = (wave >> 1) * 64, wn = (wave & 1) * 64;
    const int qr = lane >> 4, ql = lane & 15;

    __shared__ _Float16 sA[128 * 64];
    __shared__ _Float16 sB[128 * 64];

    const _Float16* Ab = A + (long long)bz * batchA + (long long)m0 * lda;
    const _Float16* Bb = B + (long long)bz * batchB + (long long)n0 * ldb;

    int kIters = K / 64;
    if (EPI == 2) kIters = (tm + 1) * 2;   // E is zero beyond (tm+1)*128

    f32x4 acc[4][4];
#pragma unroll
    for (int i = 0; i < 4; ++i)
#pragma unroll
        for (int j = 0; j < 4; ++j) acc[i][j] = (f32x4){0.f, 0.f, 0.f, 0.f};

    // Staging: 16B chunk c = t*256 + tid at LDS offset c*16B; data stored
    // there is global chunk (c&7)^(row&7), row=c>>3 (XOR swizzle, readers
    // apply the same XOR -> conflict-free b128 on both sides).
    int srow[4], sgc[4];
#pragma unroll
    for (int t = 0; t < 4; ++t) {
        const int c = t * 256 + tid;
        const int r = c >> 3;
        srow[t] = r;
        sgc[t]  = (c & 7) ^ (r & 7);
    }

    // Prologue: load tile 0 into registers
    f16x8 pa[4], pb[4];
#pragma unroll
    for (int t = 0; t < 4; ++t) {
        pa[t] = *(const f16x8*)(Ab + (long long)srow[t] * lda + sgc[t] * 8);
        pb[t] = *(const f16x8*)(Bb + (long long)srow[t] * ldb + sgc[t] * 8);
    }

    for (int kt = 0; kt < kIters; ++kt) {
        // commit prefetched tile kt to LDS (vmcnt wait happens here)
#pragma unroll
        for (int t = 0; t < 4; ++t) ((f16x8*)sA)[t * 256 + tid] = pa[t];
#pragma unroll
        for (int t = 0; t < 4; ++t) ((f16x8*)sB)[t * 256 + tid] = pb[t];
        __syncthreads();

        // issue loads for tile kt+1 now; they fly during ds_read + MFMA
        if (kt + 1 < kIters) {
            const int kk = (kt + 1) * 64;
#pragma unroll
            for (int t = 0; t < 4; ++t) {
                pa[t] = *(const f16x8*)(Ab + (long long)srow[t] * lda + kk + sgc[t] * 8);
                pb[t] = *(const f16x8*)(Bb + (long long)srow[t] * ldb + kk + sgc[t] * 8);
            }
        }

#pragma unroll
        for (int ks = 0; ks < 2; ++ks) {
            f16x8 aF[4], bF[4];
#pragma unroll
            for (int mi = 0; mi < 4; ++mi) {
                const int r = wm + mi * 16 + ql;
                const int sc = (ks * 4 + qr) ^ (r & 7);
                aF[mi] = *(const f16x8*)&sA[r * 64 + sc * 8];
            }
#pragma unroll
            for (int ni = 0; ni < 4; ++ni) {
                const int r = wn + ni * 16 + ql;
                const int sc = (ks * 4 + qr) ^ (r & 7);
                bF[ni] = *(const f16x8*)&sB[r * 64 + sc * 8];
            }
#pragma unroll
            for (int mi = 0; mi < 4; ++mi)
#pragma unroll
                for (int ni = 0; ni < 4; ++ni)
                    acc[mi][ni] = __builtin_amdgcn_mfma_f32_16x16x32_f16(
                        aF[mi], bF[ni], acc[mi][ni], 0, 0, 0);
        }
        __syncthreads();   // protect LDS before next ds_write
    }

    // Epilogue. C/D frag: col = lane&15, row = (lane>>4)*4 + r
    const long long zC = (long long)bz * batchC;
    float rsum[4][4];   // [mi][r] partial row sums (EPI==1)
    if (EPI == 1) {
#pragma unroll
        for (int mi = 0; mi < 4; ++mi)
#pragma unroll
            for (int r = 0; r < 4; ++r) rsum[mi][r] = 0.f;
    }

#pragma unroll
    for (int mi = 0; mi < 4; ++mi) {
#pragma unroll
        for (int ni = 0; ni < 4; ++ni) {
            const f32x4 v = acc[mi][ni];
            const int mbase = m0 + wm + mi * 16 + qr * 4;
            const int n     = n0 + wn + ni * 16 + ql;
#pragma unroll
            for (int r = 0; r < 4; ++r) {
                const int m = mbase + r;
                const float val = v[r];
                if (EPI == 0) {
                    const int b = m >> 11, s = m & 2047;
                    if (n < 768)
                        OQ[(long long)m * 768 + n] = (_Float16)val;
                    else if (n < 1536)
                        OKk[(long long)m * 768 + (n - 768)] = (_Float16)val;
                    else
                        OV[((long long)b * 768 + (n - 1536)) * 2048 + s] = (_Float16)val;
                } else if (EPI == 1) {
                    // n<=m always true for tn<tm; masks diagonal tile only
                    const float e = (n <= m) ? __expf(val * SOFTMAX_SCALE) : 0.f;
                    CH[zC + (long long)m * ldc + n] = (_Float16)e;
                    rsum[mi][r] += e;
                } else {
                    const float invl = 1.f / rowsum[bz * 2048 + m];
                    CF[zC + (long long)m * ldc + n] = val * invl;
                }
            }
        }
    }

    if (EPI == 1) {
        // reduce across the 16 ql-lanes (same rows), then atomicAdd per row
#pragma unroll
        for (int mi = 0; mi < 4; ++mi)
#pragma unroll
            for (int r = 0; r < 4; ++r) {
                float s = rsum[mi][r];
                s += __shfl_xor(s, 1);
                s += __shfl_xor(s, 2);
                s += __shfl_xor(s, 4);
                s += __shfl_xor(s, 8);
                if (ql == 0) {
                    const int m = m0 + wm + mi * 16 + qr * 4 + r;
                    atomicAdd(&rowsum[bz * 2048 + m], s);
                }
            }
    }
}

__global__ __launch_bounds__(256) void cvt_x(
    const float* __restrict__ in, _Float16* __restrict__ out)
{
    const int i = blockIdx.x * 256 + threadIdx.x;   // one per 8 elements
    const float4 v0 = ((const float4*)in)[i * 2];
    const float4 v1 = ((const float4*)in)[i * 2 + 1];
    f16x8 o = { (_Float16)v0.x, (_Float16)v0.y, (_Float16)v0.z, (_Float16)v0.w,
                (_Float16)v1.x, (_Float16)v1.y, (_Float16)v1.z, (_Float16)v1.w };
    ((f16x8*)out)[i] = o;
}

__global__ __launch_bounds__(256) void cvt_w3(
    const float* __restrict__ s0, const float* __restrict__ s1,
    const float* __restrict__ s2, _Float16* __restrict__ out)
{
    const int idx = blockIdx.x * 256 + threadIdx.x;  // one per 8 elements
    const int per = 768 * 768 / 8;
    const int w = idx / per;                         // wave-uniform
    const float* s = (w == 0) ? s0 : (w == 1) ? s1 : s2;
    const int lo = idx - w * per;
    const float4 v0 = ((const float4*)s)[lo * 2];
    const float4 v1 = ((const float4*)s)[lo * 2 + 1];
    f16x8 o = { (_Float16)v0.x, (_Float16)v0.y, (_Float16)v0.z, (_Float16)v0.w,
                (_Float16)v1.x, (_Float16)v1.y, (_Float16)v1.z, (_Float16)v1.w };
    ((f16x8*)out)[idx] = o;
}

extern "C" void kernel_launch(void* const* d_in, const int* in_sizes, int n_in,
                              void* d_out, int out_size, void* d_ws, size_t ws_size,
                              hipStream_t stream) {
    const float* x  = (const float*)d_in[0];
    const float* wq = (const float*)d_in[1];
    const float* wk = (const float*)d_in[2];
    const float* wv = (const float*)d_in[3];
    float* out = (float*)d_out;
    char* ws = (char*)d_ws;

    size_t off = 0;
    auto alloc = [&](size_t bytes) {
        void* p = ws + off;
        off = (off + bytes + 255) & ~(size_t)255;
        return p;
    };
    _Float16* xh = (_Float16*)alloc(8192ll * 768 * 2);
    _Float16* Wh = (_Float16*)alloc(2304ll * 768 * 2);
    _Float16* Qh = (_Float16*)alloc(8192ll * 768 * 2);
    _Float16* Kh = (_Float16*)alloc(8192ll * 768 * 2);
    _Float16* Vt = (_Float16*)alloc(4ll * 768 * 2048 * 2);     // V^T per batch
    _Float16* E  = (_Float16*)alloc(4ll * 2048 * 2048 * 2);    // exp(scores) f16
    float*    rs = (float*)   alloc(8192ll * 4);               // row sums

    hipMemsetAsync(rs, 0, 8192 * 4, stream);
    cvt_x<<<8192 * 768 / 8 / 256, 256, 0, stream>>>(x, xh);
    cvt_w3<<<3 * 288, 256, 0, stream>>>(wq, wk, wv, Wh);

    // Y = x * W^T : M=8192, N=2304, K=768
    gemm_bt<0><<<dim3(18, 64, 1), 256, 0, stream>>>(
        xh, Wh, nullptr, nullptr, Qh, Kh, Vt, nullptr,
        768, 768, 768, 0, 0, 0, 0);

    // E = exp(scale * Q K^T) per batch, rowsum atomics (lower triangle only)
    gemm_bt<1><<<dim3(136 * 4, 1, 1), 256, 0, stream>>>(
        Qh, Kh, nullptr, E, nullptr, nullptr, nullptr, rs,
        768, 768, 768, 2048, 2048ll * 768, 2048ll * 768, 2048ll * 2048);

    // O = (E * V^T^T) / rowsum per batch : M=2048, N=768, K causal-truncated
    gemm_bt<2><<<dim3(6, 16, 4), 256, 0, stream>>>(
        E, Vt, out, nullptr, nullptr, nullptr, nullptr, rs,
        2048, 2048, 2048, 768, 2048ll * 2048, 768ll * 2048, 2048ll * 768);
}